// Round 10
// baseline (223.327 us; speedup 1.0000x reference)
//
#include <hip/hip_runtime.h>

#define NL  4096
#define TPB 1024
#define SPT 4

typedef float v2f __attribute__((ext_vector_type(2)));

__device__ __forceinline__ float rfl(float x) {
    return __uint_as_float(__builtin_amdgcn_readfirstlane(__float_as_uint(x)));
}
__device__ __forceinline__ float fast_rcp(float x) { return __builtin_amdgcn_rcpf(x); }
__device__ __forceinline__ float fexp2(float x) { return __builtin_amdgcn_exp2f(x); }  // 2^x
__device__ __forceinline__ float flog2(float x) { return __builtin_amdgcn_logf(x); }   // log2(x)

#define L2E 1.44269504088896340736f
#define LN2 0.69314718055994530942f

// Even part of softplus in log2 domain: F(x)=log2(1+2^x)-x/2, cubic in s=x^2.
#define SP_C0 1.0f
#define SP_C1 0.0864667f
#define SP_C2 (-0.0015685f)
#define SP_C3 2.5763e-5f

// One block per row, 1024 threads x 4 steps. Whole row (80 KB) staged to LDS
// with XOR bank swizzle; affine (U,S) composition packed as float2
// (.x=U_H, .y=U_1); theta linearized; poly softplus (no trans in hot loop).
// Only boundary: global step 4095 -> dt=0 identity.
__global__ void __launch_bounds__(TPB, 8) onenet_fused(
    const float* __restrict__ X,   const float* __restrict__ SC,
    const float* __restrict__ pW1, const float* __restrict__ pb1,
    const float* __restrict__ pW2, const float* __restrict__ pb2,
    const float* __restrict__ rW1, const float* __restrict__ rb1,
    const float* __restrict__ rW2, const float* __restrict__ rb2,
    float* __restrict__ out)
{
    __shared__ float4 tile[TPB * 5];          // 80 KB; aliased for reduction later
    float* redf = (float*)tile;               // 16 waves x 9 floats

    const int row  = blockIdx.x;
    const int tid  = threadIdx.x;
    const int lane = tid & 63;
    const int w    = tid >> 6;

    // ---- staging: whole row, coalesced, swizzled ----
    const float* Xrow = X + (size_t)row * NL * 5;
    {
        const float4* gq = (const float4*)Xrow;
#pragma unroll
        for (int k = 0; k < 5; ++k) {
            int widx = tid + TPB * k;
            int sw   = widx ^ ((widx >> 3) & 7);
            tile[sw] = gq[widx];
        }
    }

    // ---- uniform weight prologue (SGPR-pinned) while staging is in flight ----
    const float LBv[5]  = {0.005f, 0.025f, 0.1f, 0.0f, 0.002f};
    const float UBLB[5] = {0.015f, 0.045f, 0.9f, 0.055f, 0.023f};

    float sc0 = rfl(SC[row * 3 + 0]);
    float sc1 = rfl(SC[row * 3 + 1]);
    float sc2 = rfl(SC[row * 3 + 2]);

    float W1S[10], W1T[10], BASE[10], V4[10];
    v2f V01[10], V23[10], AL01, AL23;
    float AL4;
#pragma unroll
    for (int j = 0; j < 10; ++j) {
        W1S[j]  = rfl(L2E * pW1[j]);
        W1T[j]  = rfl(L2E * pW1[10 + j]);
        BASE[j] = rfl(L2E * fmaf(sc0, pW1[20 + j],
                            fmaf(sc1, pW1[30 + j],
                            fmaf(sc2, pW1[40 + j], pb1[j]))));
        V01[j].x = rfl(LN2 * 0.0025f * UBLB[0] * pW2[5 * j + 0]);
        V01[j].y = rfl(LN2 * 0.0025f * UBLB[1] * pW2[5 * j + 1]);
        V23[j].x = rfl(LN2 * 0.0025f * UBLB[2] * pW2[5 * j + 2]);
        V23[j].y = rfl(LN2 * 0.0025f * UBLB[3] * pW2[5 * j + 3]);
        V4[j]    = rfl(LN2 * 0.0025f * UBLB[4] * pW2[5 * j + 4]);
    }
    AL01.x = rfl(LBv[0] + UBLB[0] * fmaf(0.0025f, pb2[0], 0.5f));
    AL01.y = rfl(LBv[1] + UBLB[1] * fmaf(0.0025f, pb2[1], 0.5f));
    AL23.x = rfl(LBv[2] + UBLB[2] * fmaf(0.0025f, pb2[2], 0.5f));
    AL23.y = rfl(LBv[3] + UBLB[3] * fmaf(0.0025f, pb2[3], 0.5f));
    AL4    = rfl(LBv[4] + UBLB[4] * fmaf(0.0025f, pb2[4], 0.5f));

    __syncthreads();                          // staging visible

    // ---- conflict-free LDS reads: this thread's 4 steps ----
    float f[20];
#pragma unroll
    for (int j = 0; j < 5; ++j) {
        int widx = 5 * tid + j;
        int sw   = widx ^ ((widx >> 3) & 7);
        *(float4*)&f[4 * j] = tile[sw];
    }
    float tn;
    {
        int wn  = 5 * ((tid + 1) & (TPB - 1));
        int swn = wn ^ ((wn >> 3) & 7);
        float tl = tile[swn].x;
        tn = (tid == TPB - 1) ? f[15] : tl;   // dt=0 -> identity at step 4095
    }

    v2f a = {1.f, 1.f}, b = {0.f, 0.f}, cS = {0.f, 0.f}, dS = {0.f, 0.f};
    float oacc = 0.f, OCV0 = 0.f, I0 = 0.f, SOC0 = 0.f, T0 = 0.f;

#pragma unroll
    for (int i = 0; i < SPT; ++i) {
        float tt = f[5 * i + 0];
        float Ii = f[5 * i + 1];
        float Tt = f[5 * i + 2];
        float SS = f[5 * i + 4];
        float tnx = (i < SPT - 1) ? f[5 * i + 5] : tn;
        float dt  = tnx - tt;
        float inv = fast_rcp(Ii);

        v2f t01 = AL01, t23 = AL23;
        float t4 = AL4;
#pragma unroll
        for (int j = 0; j < 10; ++j) {
            float pre = fmaf(SS, W1S[j], fmaf(Tt, W1T[j], BASE[j]));
            float s   = pre * pre;
            float p   = fmaf(s, SP_C3, SP_C2);
            p = fmaf(s, p, SP_C1);
            p = fmaf(s, p, SP_C0);
            float lam = fmaf(pre, 0.5f, p);   // softplus2(pre), poly approx
            v2f lam2 = {lam, lam};
            t01 = lam2 * V01[j] + t01;
            t23 = lam2 * V23[j] + t23;
            t4  = fmaf(lam, V4[j], t4);
        }
        // t01.x=R_1, t01.y=RC_r, t23.x=OCV_U, t23.y=M_Hn, t4=K_H
        oacc = fmaf(-t23.x, inv, oacc);
        if (i == 0) { OCV0 = t23.x; I0 = Ii; SOC0 = SS; T0 = Tt; }

        float g  = dt * t4 * Ii;
        float hh = dt * t01.y;
        v2f sv = {1.f + g, 1.f - hh};
        v2f bv = {g * t23.y, hh * t01.x * Ii};
        v2f iv = {inv, inv};
        cS = iv * a + cS;        // S-accum with pre-step U
        dS = iv * b + dS;
        b  = sv * b + bv;        // then apply T_l
        a  = sv * a;
    }

    // ---- wave-level order-preserving tree reduce ----
#pragma unroll
    for (int off = 1; off < 64; off <<= 1) {
        v2f a2, b2, c2, d2;
        a2.x = __shfl_down(a.x, off);  a2.y = __shfl_down(a.y, off);
        b2.x = __shfl_down(b.x, off);  b2.y = __shfl_down(b.y, off);
        c2.x = __shfl_down(cS.x, off); c2.y = __shfl_down(cS.y, off);
        d2.x = __shfl_down(dS.x, off); d2.y = __shfl_down(dS.y, off);
        float o2 = __shfl_down(oacc, off);
        v2f nb = a2 * b + b2;
        v2f nc = c2 * a + cS;
        v2f nd = (dS + d2) + c2 * b;
        a = a2 * a; b = nb; cS = nc; dS = nd;
        oacc += o2;
    }

    __syncthreads();                          // all tile reads done; alias safe
    if (lane == 0) {
        float* rp = redf + w * 9;
        rp[0] = a.x;  rp[1] = a.y;
        rp[2] = b.x;  rp[3] = b.y;
        rp[4] = cS.x; rp[5] = cS.y;
        rp[6] = dS.x; rp[7] = dS.y;
        rp[8] = oacc;
    }
    __syncthreads();

    if (tid == 0) {
#pragma unroll
        for (int k = 1; k < TPB / 64; ++k) {
            const float* rp = redf + k * 9;
            v2f ak, bk, ck, dk;
            ak.x = rp[0]; ak.y = rp[1];
            bk.x = rp[2]; bk.y = rp[3];
            ck.x = rp[4]; ck.y = rp[5];
            dk.x = rp[6]; dk.y = rp[7];
            v2f nb = ak * b + bk;
            v2f nc = ck * a + cS;
            v2f nd = (dS + dk) + ck * b;
            a = ak * a; b = nb; cS = nc; dS = nd;
            oacc += rp[8];
        }
        // r-net on x[row,0,:] = [SOC0, T0, sc0, sc1, sc2] (one-off, exact trans)
        float u = rb1[0];
        u = fmaf(SOC0, rW1[0], u);
        u = fmaf(T0,   rW1[1], u);
        u = fmaf(sc0,  rW1[2], u);
        u = fmaf(sc1,  rW1[3], u);
        u = fmaf(sc2,  rW1[4], u);
        float sp  = LN2 * flog2(1.0f + fexp2(L2E * u));
        float r   = fmaf(sp, rW2[0], rb2[0]);
        float Rs  = sc2 * (1.0f + r);
        float U10 = -OCV0 - I0 * Rs;          // U_H0 = 0
        float SH  = dS.x;                     // sum U_H/I
        float S1  = fmaf(cS.y, U10, dS.y);    // sum U_1/I
        out[row]  = (oacc - SH - S1) * (1.0f / 4096.0f);
    }
}

extern "C" void kernel_launch(void* const* d_in, const int* in_sizes, int n_in,
                              void* d_out, int out_size, void* d_ws, size_t ws_size,
                              hipStream_t stream) {
    const float* X   = (const float*)d_in[0];
    const float* SC  = (const float*)d_in[1];
    const float* pW1 = (const float*)d_in[2];
    const float* pb1 = (const float*)d_in[3];
    const float* pW2 = (const float*)d_in[4];
    const float* pb2 = (const float*)d_in[5];
    const float* rW1 = (const float*)d_in[6];
    const float* rb1 = (const float*)d_in[7];
    const float* rW2 = (const float*)d_in[8];
    const float* rb2 = (const float*)d_in[9];
    float* out = (float*)d_out;

    onenet_fused<<<1024, TPB, 0, stream>>>(X, SC, pW1, pb1, pW2, pb2,
                                           rW1, rb1, rW2, rb2, out);
}